// Round 7
// baseline (10952.180 us; speedup 1.0000x reference)
//
#include <hip/hip_runtime.h>

#define KC 256
#define DIM 64
#define NITER 10
#define KTILE 64   // clusters staged in LDS at a time (16 KiB)

// numpy pairwise sum for 64 elements, inputs already rounded f32:
// r[j] = a[j]+a[j+8]+...+a[j+56] (sequential), then ((r0+r1)+(r2+r3))+((r4+r5)+(r6+r7))
__device__ __forceinline__ float np_pairwise_sq64(const float* a) {
    float r[8];
#pragma unroll
    for (int j = 0; j < 8; ++j) r[j] = __fmul_rn(a[j], a[j]);
#pragma unroll
    for (int i = 8; i < 64; i += 8)
#pragma unroll
        for (int j = 0; j < 8; ++j)
            r[j] = __fadd_rn(r[j], __fmul_rn(a[i + j], a[i + j]));
    float t01 = __fadd_rn(r[0], r[1]), t23 = __fadd_rn(r[2], r[3]);
    float t45 = __fadd_rn(r[4], r[5]), t67 = __fadd_rn(r[6], r[7]);
    return __fadd_rn(__fadd_rn(t01, t23), __fadd_rn(t45, t67));
}

// ---------------- init: c = x[:K] ----------------
__global__ void init_k(const float* __restrict__ x, float* __restrict__ c) {
    const int idx = blockIdx.x * 256 + threadIdx.x;
    if (idx < KC * DIM) c[idx] = x[idx];
}

// ---------------- assign (+ per-block label histogram), LDS-tiled c ----------------
__global__ __launch_bounds__(256, 4) void assign_hist_k(
    const float* __restrict__ x, const float* __restrict__ c,
    float* __restrict__ labels, int* __restrict__ hist, int n)
{
    __shared__ float c_lds[KTILE * DIM];   // 16 KiB tile of centroids
    __shared__ float csq[KC];
    __shared__ int whist[4 * KC];
    const int t = threadIdx.x;

    for (int j = t; j < 4 * KC; j += 256) whist[j] = 0;
    if (t < KC) {
        float cr[DIM];
        const float4* cp = reinterpret_cast<const float4*>(c + t * DIM);
#pragma unroll
        for (int j = 0; j < DIM / 4; ++j) {
            float4 v = cp[j];
            cr[4 * j + 0] = v.x; cr[4 * j + 1] = v.y;
            cr[4 * j + 2] = v.z; cr[4 * j + 3] = v.w;
        }
        csq[t] = np_pairwise_sq64(cr);
    }

    const int i = blockIdx.x * 256 + t;
    const bool valid = (i < n);
    const int isafe = valid ? i : 0;

    float xr[DIM];
    const float4* xv = reinterpret_cast<const float4*>(x + (size_t)isafe * DIM);
#pragma unroll
    for (int j = 0; j < DIM / 4; ++j) {
        float4 v = xv[j];
        xr[4 * j + 0] = v.x; xr[4 * j + 1] = v.y;
        xr[4 * j + 2] = v.z; xr[4 * j + 3] = v.w;
    }
    const float xsq = np_pairwise_sq64(xr);

    float best = __int_as_float(0x7f800000);
    int bk = 0;
    int nanIdx = -1;

    for (int tile = 0; tile < KC; tile += KTILE) {
        __syncthreads();   // also covers csq/whist init on first pass
        // stage 64 clusters (coalesced float4): 4 loads per thread
        {
            const float4* src = reinterpret_cast<const float4*>(c + (size_t)tile * DIM);
            float4* dst = reinterpret_cast<float4*>(c_lds);
            for (int j = t; j < KTILE * DIM / 4; j += 256) dst[j] = src[j];
        }
        __syncthreads();

        for (int k0 = 0; k0 < KTILE; k0 += 8) {
            float acc[8];
#pragma unroll
            for (int u = 0; u < 8; ++u) acc[u] = 0.0f;
#pragma unroll
            for (int db = 0; db < DIM / 4; ++db) {
                float4 cv[8];
#pragma unroll
                for (int u = 0; u < 8; ++u)
                    cv[u] = *reinterpret_cast<const float4*>(c_lds + (k0 + u) * DIM + db * 4);
                const float x0 = xr[4 * db + 0], x1 = xr[4 * db + 1];
                const float x2 = xr[4 * db + 2], x3 = xr[4 * db + 3];
#pragma unroll
                for (int u = 0; u < 8; ++u) {
                    acc[u] = fmaf(x0, cv[u].x, acc[u]);
                    acc[u] = fmaf(x1, cv[u].y, acc[u]);
                    acc[u] = fmaf(x2, cv[u].z, acc[u]);
                    acc[u] = fmaf(x3, cv[u].w, acc[u]);
                }
            }
#pragma unroll
            for (int u = 0; u < 8; ++u) {
                const int kk = tile + k0 + u;
                const float dist = __fadd_rn(__fsub_rn(xsq, 2.0f * acc[u]), csq[kk]);
                if (dist < best) { best = dist; bk = kk; }
                if (nanIdx < 0 && dist != dist) nanIdx = kk;   // numpy: first NaN wins
            }
        }
    }

    int lbl = 0;
    if (valid) {
        lbl = (nanIdx >= 0 ? nanIdx : bk);
        labels[i] = (float)lbl;
    }

    // ballot-based per-wave group counts (deterministic)
    const int lane = t & 63, w = t >> 6;
    unsigned long long same = __ballot(valid);
#pragma unroll
    for (int bit = 0; bit < 8; ++bit) {
        unsigned long long bb = __ballot((lbl >> bit) & 1);
        same &= ((lbl >> bit) & 1) ? bb : ~bb;
    }
    if (valid && lane == __builtin_ctzll(same))
        whist[w * KC + lbl] = (int)__popcll(same);
    __syncthreads();
    if (t < KC)
        hist[(size_t)blockIdx.x * KC + t] =
            whist[t] + whist[KC + t] + whist[2 * KC + t] + whist[3 * KC + t];
}

// ---------------- scan1: per-cluster exclusive prefix over blocks ----------------
__global__ __launch_bounds__(256) void scan1_k(
    int* __restrict__ hist, int nb, int* __restrict__ cnt)
{
    __shared__ int sbuf[256];
    const int k = blockIdx.x;          // cluster
    const int t = threadIdx.x;
    const int epb = (nb + 255) / 256;  // entries per thread
    const int b0 = t * epb;

    // chunk sum
    int s = 0;
    for (int u = 0; u < epb; ++u) {
        const int b = b0 + u;
        if (b < nb) s += hist[(size_t)b * KC + k];
    }
    // Hillis-Steele inclusive scan of chunk sums
    sbuf[t] = s;
    __syncthreads();
    int incl = s;
#pragma unroll
    for (int d = 1; d < 256; d <<= 1) {
        const int v = (t >= d) ? sbuf[t - d] : 0;
        __syncthreads();
        incl += v;
        sbuf[t] = incl;
        __syncthreads();
    }
    int run = incl - s;                // exclusive base for this chunk
    for (int u = 0; u < epb; ++u) {
        const int b = b0 + u;
        if (b < nb) {
            const int v = hist[(size_t)b * KC + k];
            hist[(size_t)b * KC + k] = run;
            run += v;
        }
    }
    if (t == 255) cnt[k] = incl;       // total count for cluster k
}

// ---------------- scan2: cluster bases (padded to 4) ----------------
__global__ __launch_bounds__(256) void scan2_k(
    const int* __restrict__ cnt, int* __restrict__ base)
{
    __shared__ int sbuf[256];
    const int t = threadIdx.x;
    const int padded = (cnt[t] + 3) & ~3;
    sbuf[t] = padded;
    __syncthreads();
    int incl = padded;
#pragma unroll
    for (int d = 1; d < 256; d <<= 1) {
        const int v = (t >= d) ? sbuf[t - d] : 0;
        __syncthreads();
        incl += v;
        sbuf[t] = incl;
        __syncthreads();
    }
    base[t] = incl - padded;
}

// ---------------- scatter: stable counting-sort placement (into padded segments) ----------------
__global__ __launch_bounds__(256) void scatter_k(
    const float* __restrict__ labels, const int* __restrict__ hist,
    const int* __restrict__ base, int* __restrict__ order, int n)
{
    __shared__ int whist[4 * KC];
    const int t = threadIdx.x;
    for (int j = t; j < 4 * KC; j += 256) whist[j] = 0;
    __syncthreads();

    const int i = blockIdx.x * 256 + t;
    const bool valid = (i < n);
    const int lbl = valid ? (int)labels[i] : 0;
    const int lane = t & 63, w = t >> 6;

    unsigned long long same = __ballot(valid);
#pragma unroll
    for (int bit = 0; bit < 8; ++bit) {
        unsigned long long bb = __ballot((lbl >> bit) & 1);
        same &= ((lbl >> bit) & 1) ? bb : ~bb;
    }
    const unsigned long long below = (1ull << lane) - 1ull;
    const int rank_wave = (int)__popcll(same & below);
    if (valid && lane == __builtin_ctzll(same))
        whist[w * KC + lbl] = (int)__popcll(same);
    __syncthreads();

    if (valid) {
        int off = rank_wave;
        for (int ww = 0; ww < w; ++ww) off += whist[ww * KC + lbl];
        const int pos = base[lbl] + hist[(size_t)blockIdx.x * KC + lbl] + off;
        order[pos] = i;
    }
}

// ---------------- permute + transpose: buf[d][pos] = x[order[pos]][d] ----------------
__global__ __launch_bounds__(256) void transpose_k(
    const float* __restrict__ x, const int* __restrict__ order,
    float* __restrict__ buf, int nstride)
{
    __shared__ float tile[64][65];
    __shared__ int idxs[64];
    const int t = threadIdx.x;
    const int p0 = blockIdx.x * 64;
    if (t < 64) idxs[t] = order[p0 + t];
    __syncthreads();
    const int w = t >> 6, lane = t & 63;
#pragma unroll
    for (int r = 0; r < 16; ++r) {
        const int row = w * 16 + r;
        tile[row][lane] = x[(size_t)idxs[row] * DIM + lane];   // coalesced 256B row read
    }
    __syncthreads();
#pragma unroll
    for (int r = 0; r < 16; ++r) {
        const int d = w * 16 + r;
        buf[(size_t)d * nstride + p0 + lane] = tile[lane][d];  // coalesced 256B write
    }
}

// ---------------- sum: contiguous float4 streams, exact ascending-order f32 chain ----------------
__global__ __launch_bounds__(64) void sum_k(
    const float* __restrict__ buf, const int* __restrict__ base,
    const int* __restrict__ cnt, float* __restrict__ c, int nstride)
{
    const int k = blockIdx.x;
    const int lane = threadIdx.x;          // = dim
    const int b0 = base[k];                // multiple of 4 -> 16B aligned
    const int ct = cnt[k];
    const float* s = buf + (size_t)lane * nstride + b0;

    float acc = 0.0f;
    int j = 0;
    const int ct4 = ct & ~3;
    for (; j + 32 <= ct4; j += 32) {
        float4 v[8];
#pragma unroll
        for (int u = 0; u < 8; ++u)
            v[u] = *reinterpret_cast<const float4*>(s + j + 4 * u);  // 8 loads in flight
#pragma unroll
        for (int u = 0; u < 8; ++u) {
            acc = __fadd_rn(acc, v[u].x); acc = __fadd_rn(acc, v[u].y);
            acc = __fadd_rn(acc, v[u].z); acc = __fadd_rn(acc, v[u].w);
        }
    }
    for (; j + 4 <= ct4; j += 4) {
        float4 v = *reinterpret_cast<const float4*>(s + j);
        acc = __fadd_rn(acc, v.x); acc = __fadd_rn(acc, v.y);
        acc = __fadd_rn(acc, v.z); acc = __fadd_rn(acc, v.w);
    }
    for (; j < ct; ++j) acc = __fadd_rn(acc, s[j]);

    c[k * DIM + lane] = __fdiv_rn(acc, (float)ct);   // 0/0 -> NaN matches ref
}

// ---------------- fallback gather (round-5 proven) ----------------
__global__ __launch_bounds__(64) void gather_k(
    const float* __restrict__ x, const int* __restrict__ order,
    const int* __restrict__ base, const int* __restrict__ cnt,
    float* __restrict__ c)
{
    const int k = blockIdx.x;
    const int lane = threadIdx.x;
    const int b0 = base[k];
    const int ct = cnt[k];
    float acc = 0.0f;
    int j = 0;
    for (; j + 32 <= ct; j += 32) {
        float v[32];
#pragma unroll
        for (int u = 0; u < 32; ++u)
            v[u] = x[(size_t)order[b0 + j + u] * DIM + lane];
#pragma unroll
        for (int u = 0; u < 32; ++u) acc = __fadd_rn(acc, v[u]);
    }
    for (; j < ct; ++j)
        acc = __fadd_rn(acc, x[(size_t)order[b0 + j] * DIM + lane]);
    c[k * DIM + lane] = __fdiv_rn(acc, (float)ct);
}

extern "C" void kernel_launch(void* const* d_in, const int* in_sizes, int n_in,
                              void* d_out, int out_size, void* d_ws, size_t ws_size,
                              hipStream_t stream)
{
    const float* x = (const float*)d_in[0];
    const int n = in_sizes[0] / DIM;          // 262144

    float* out_c = (float*)d_out;             // [256*64] centroids (working buffer too)
    float* out_labels = out_c + KC * DIM;     // [n] labels as floats

    const int nb = (n + 255) / 256;           // 1024
    const int nstride = n + 1024;             // padded sorted-position stride

    // workspace layout (256B-aligned blocks)
    size_t off = 0;
    auto alloc = [&](size_t bytes) -> size_t {
        size_t o = off; off = (off + bytes + 255) & ~(size_t)255; return o;
    };
    char* w = (char*)d_ws;
    int*   hist  = (int*)(w + alloc((size_t)nb * KC * sizeof(int)));
    int*   base  = (int*)(w + alloc(KC * sizeof(int)));
    int*   cnt   = (int*)(w + alloc(KC * sizeof(int)));
    int*   order = (int*)(w + alloc((size_t)nstride * sizeof(int)));
    const size_t med_need = off;
    float* buf   = (float*)(w + alloc((size_t)DIM * nstride * sizeof(float)));
    const size_t big_need = off;

    const bool big = (ws_size >= big_need);
    const bool med = (ws_size >= med_need);

    init_k<<<(KC * DIM + 255) / 256, 256, 0, stream>>>(x, out_c);
    if (big)  // pad slots of order must hold valid indices before first transpose
        hipMemsetAsync(order, 0, (size_t)nstride * sizeof(int), stream);

    for (int it = 0; it < NITER; ++it) {
        assign_hist_k<<<nb, 256, 0, stream>>>(x, out_c, out_labels, hist, n);
        if (med) {
            scan1_k<<<KC, 256, 0, stream>>>(hist, nb, cnt);
            scan2_k<<<1, 256, 0, stream>>>(cnt, base);
            scatter_k<<<nb, 256, 0, stream>>>(out_labels, hist, base, order, n);
            if (big) {
                transpose_k<<<nstride / 64, 256, 0, stream>>>(x, order, buf, nstride);
                sum_k<<<KC, 64, 0, stream>>>(buf, base, cnt, out_c, nstride);
            } else {
                gather_k<<<KC, 64, 0, stream>>>(x, order, base, cnt, out_c);
            }
        }
    }
}

// Round 8
// 3492.000 us; speedup vs baseline: 3.1364x; 3.1364x over previous
//
#include <hip/hip_runtime.h>

#define KC 256
#define DIM 64
#define NITER 10
#define KTILE 64   // clusters staged in LDS at a time (16 KiB)

// numpy pairwise sum for 64 elements, inputs already rounded f32:
// r[j] = a[j]+a[j+8]+...+a[j+56] (sequential), then ((r0+r1)+(r2+r3))+((r4+r5)+(r6+r7))
__device__ __forceinline__ float np_pairwise_sq64(const float* a) {
    float r[8];
#pragma unroll
    for (int j = 0; j < 8; ++j) r[j] = __fmul_rn(a[j], a[j]);
#pragma unroll
    for (int i = 8; i < 64; i += 8)
#pragma unroll
        for (int j = 0; j < 8; ++j)
            r[j] = __fadd_rn(r[j], __fmul_rn(a[i + j], a[i + j]));
    float t01 = __fadd_rn(r[0], r[1]), t23 = __fadd_rn(r[2], r[3]);
    float t45 = __fadd_rn(r[4], r[5]), t67 = __fadd_rn(r[6], r[7]);
    return __fadd_rn(__fadd_rn(t01, t23), __fadd_rn(t45, t67));
}

// ---------------- init: c = x[:K] ----------------
__global__ void init_k(const float* __restrict__ x, float* __restrict__ c) {
    const int idx = blockIdx.x * 256 + threadIdx.x;
    if (idx < KC * DIM) c[idx] = x[idx];
}

// ---------------- assign (+ per-block label histogram), LDS-tiled c ----------------
// NOTE: plain __launch_bounds__(256). The (256,4) min-waves clamp in the previous
// round forced VGPR=64 and spilled xr[64] to scratch (FETCH_SIZE 2.1 GB/dispatch).
__global__ __launch_bounds__(256) void assign_hist_k(
    const float* __restrict__ x, const float* __restrict__ c,
    float* __restrict__ labels, int* __restrict__ hist, int n)
{
    __shared__ float c_lds[KTILE * DIM];   // 16 KiB tile of centroids
    __shared__ float csq[KC];
    __shared__ int whist[4 * KC];
    const int t = threadIdx.x;

    for (int j = t; j < 4 * KC; j += 256) whist[j] = 0;
    if (t < KC) {
        float cr[DIM];
        const float4* cp = reinterpret_cast<const float4*>(c + t * DIM);
#pragma unroll
        for (int j = 0; j < DIM / 4; ++j) {
            float4 v = cp[j];
            cr[4 * j + 0] = v.x; cr[4 * j + 1] = v.y;
            cr[4 * j + 2] = v.z; cr[4 * j + 3] = v.w;
        }
        csq[t] = np_pairwise_sq64(cr);
    }

    const int i = blockIdx.x * 256 + t;
    const bool valid = (i < n);
    const int isafe = valid ? i : 0;

    float xr[DIM];
    const float4* xv = reinterpret_cast<const float4*>(x + (size_t)isafe * DIM);
#pragma unroll
    for (int j = 0; j < DIM / 4; ++j) {
        float4 v = xv[j];
        xr[4 * j + 0] = v.x; xr[4 * j + 1] = v.y;
        xr[4 * j + 2] = v.z; xr[4 * j + 3] = v.w;
    }
    const float xsq = np_pairwise_sq64(xr);

    float best = __int_as_float(0x7f800000);
    int bk = 0;
    int nanIdx = -1;

    for (int tile = 0; tile < KC; tile += KTILE) {
        __syncthreads();   // also covers csq/whist init on first pass
        // stage 64 clusters (coalesced float4): 4 loads per thread
        {
            const float4* src = reinterpret_cast<const float4*>(c + (size_t)tile * DIM);
            float4* dst = reinterpret_cast<float4*>(c_lds);
            for (int j = t; j < KTILE * DIM / 4; j += 256) dst[j] = src[j];
        }
        __syncthreads();

        for (int k0 = 0; k0 < KTILE; k0 += 8) {
            float acc[8];
#pragma unroll
            for (int u = 0; u < 8; ++u) acc[u] = 0.0f;
#pragma unroll
            for (int db = 0; db < DIM / 4; ++db) {
                float4 cv[8];
#pragma unroll
                for (int u = 0; u < 8; ++u)
                    cv[u] = *reinterpret_cast<const float4*>(c_lds + (k0 + u) * DIM + db * 4);
                const float x0 = xr[4 * db + 0], x1 = xr[4 * db + 1];
                const float x2 = xr[4 * db + 2], x3 = xr[4 * db + 3];
#pragma unroll
                for (int u = 0; u < 8; ++u) {
                    acc[u] = fmaf(x0, cv[u].x, acc[u]);
                    acc[u] = fmaf(x1, cv[u].y, acc[u]);
                    acc[u] = fmaf(x2, cv[u].z, acc[u]);
                    acc[u] = fmaf(x3, cv[u].w, acc[u]);
                }
            }
#pragma unroll
            for (int u = 0; u < 8; ++u) {
                const int kk = tile + k0 + u;
                const float dist = __fadd_rn(__fsub_rn(xsq, 2.0f * acc[u]), csq[kk]);
                if (dist < best) { best = dist; bk = kk; }
                if (nanIdx < 0 && dist != dist) nanIdx = kk;   // numpy: first NaN wins
            }
        }
    }

    int lbl = 0;
    if (valid) {
        lbl = (nanIdx >= 0 ? nanIdx : bk);
        labels[i] = (float)lbl;
    }

    // ballot-based per-wave group counts (deterministic)
    const int lane = t & 63, w = t >> 6;
    unsigned long long same = __ballot(valid);
#pragma unroll
    for (int bit = 0; bit < 8; ++bit) {
        unsigned long long bb = __ballot((lbl >> bit) & 1);
        same &= ((lbl >> bit) & 1) ? bb : ~bb;
    }
    if (valid && lane == __builtin_ctzll(same))
        whist[w * KC + lbl] = (int)__popcll(same);
    __syncthreads();
    if (t < KC)
        hist[(size_t)blockIdx.x * KC + t] =
            whist[t] + whist[KC + t] + whist[2 * KC + t] + whist[3 * KC + t];
}

// ---------------- scan1: per-cluster exclusive prefix over blocks ----------------
__global__ __launch_bounds__(256) void scan1_k(
    int* __restrict__ hist, int nb, int* __restrict__ cnt)
{
    __shared__ int sbuf[256];
    const int k = blockIdx.x;          // cluster
    const int t = threadIdx.x;
    const int epb = (nb + 255) / 256;  // entries per thread
    const int b0 = t * epb;

    int s = 0;
    for (int u = 0; u < epb; ++u) {
        const int b = b0 + u;
        if (b < nb) s += hist[(size_t)b * KC + k];
    }
    sbuf[t] = s;
    __syncthreads();
    int incl = s;
#pragma unroll
    for (int d = 1; d < 256; d <<= 1) {
        const int v = (t >= d) ? sbuf[t - d] : 0;
        __syncthreads();
        incl += v;
        sbuf[t] = incl;
        __syncthreads();
    }
    int run = incl - s;                // exclusive base for this chunk
    for (int u = 0; u < epb; ++u) {
        const int b = b0 + u;
        if (b < nb) {
            const int v = hist[(size_t)b * KC + k];
            hist[(size_t)b * KC + k] = run;
            run += v;
        }
    }
    if (t == 255) cnt[k] = incl;       // total count for cluster k
}

// ---------------- scan2: cluster bases (padded to 4) ----------------
__global__ __launch_bounds__(256) void scan2_k(
    const int* __restrict__ cnt, int* __restrict__ base)
{
    __shared__ int sbuf[256];
    const int t = threadIdx.x;
    const int padded = (cnt[t] + 3) & ~3;
    sbuf[t] = padded;
    __syncthreads();
    int incl = padded;
#pragma unroll
    for (int d = 1; d < 256; d <<= 1) {
        const int v = (t >= d) ? sbuf[t - d] : 0;
        __syncthreads();
        incl += v;
        sbuf[t] = incl;
        __syncthreads();
    }
    base[t] = incl - padded;
}

// ---------------- scatter: stable counting-sort placement (into padded segments) ----------------
__global__ __launch_bounds__(256) void scatter_k(
    const float* __restrict__ labels, const int* __restrict__ hist,
    const int* __restrict__ base, int* __restrict__ order, int n)
{
    __shared__ int whist[4 * KC];
    const int t = threadIdx.x;
    for (int j = t; j < 4 * KC; j += 256) whist[j] = 0;
    __syncthreads();

    const int i = blockIdx.x * 256 + t;
    const bool valid = (i < n);
    const int lbl = valid ? (int)labels[i] : 0;
    const int lane = t & 63, w = t >> 6;

    unsigned long long same = __ballot(valid);
#pragma unroll
    for (int bit = 0; bit < 8; ++bit) {
        unsigned long long bb = __ballot((lbl >> bit) & 1);
        same &= ((lbl >> bit) & 1) ? bb : ~bb;
    }
    const unsigned long long below = (1ull << lane) - 1ull;
    const int rank_wave = (int)__popcll(same & below);
    if (valid && lane == __builtin_ctzll(same))
        whist[w * KC + lbl] = (int)__popcll(same);
    __syncthreads();

    if (valid) {
        int off = rank_wave;
        for (int ww = 0; ww < w; ++ww) off += whist[ww * KC + lbl];
        const int pos = base[lbl] + hist[(size_t)blockIdx.x * KC + lbl] + off;
        order[pos] = i;
    }
}

// ---------------- permute + transpose: buf[d][pos] = x[order[pos]][d] ----------------
__global__ __launch_bounds__(256) void transpose_k(
    const float* __restrict__ x, const int* __restrict__ order,
    float* __restrict__ buf, int nstride)
{
    __shared__ float tile[64][65];
    __shared__ int idxs[64];
    const int t = threadIdx.x;
    const int p0 = blockIdx.x * 64;
    if (t < 64) idxs[t] = order[p0 + t];
    __syncthreads();
    const int w = t >> 6, lane = t & 63;
#pragma unroll
    for (int r = 0; r < 16; ++r) {
        const int row = w * 16 + r;
        tile[row][lane] = x[(size_t)idxs[row] * DIM + lane];   // coalesced 256B row read
    }
    __syncthreads();
#pragma unroll
    for (int r = 0; r < 16; ++r) {
        const int d = w * 16 + r;
        buf[(size_t)d * nstride + p0 + lane] = tile[lane][d];  // coalesced 256B write
    }
}

// ---------------- sum: contiguous float4 streams, exact ascending-order f32 chain ----------------
__global__ __launch_bounds__(64) void sum_k(
    const float* __restrict__ buf, const int* __restrict__ base,
    const int* __restrict__ cnt, float* __restrict__ c, int nstride)
{
    const int k = blockIdx.x;
    const int lane = threadIdx.x;          // = dim
    const int b0 = base[k];                // multiple of 4 -> 16B aligned
    const int ct = cnt[k];
    const float* s = buf + (size_t)lane * nstride + b0;

    float acc = 0.0f;
    int j = 0;
    const int ct4 = ct & ~3;
    for (; j + 32 <= ct4; j += 32) {
        float4 v[8];
#pragma unroll
        for (int u = 0; u < 8; ++u)
            v[u] = *reinterpret_cast<const float4*>(s + j + 4 * u);  // 8 loads in flight
#pragma unroll
        for (int u = 0; u < 8; ++u) {
            acc = __fadd_rn(acc, v[u].x); acc = __fadd_rn(acc, v[u].y);
            acc = __fadd_rn(acc, v[u].z); acc = __fadd_rn(acc, v[u].w);
        }
    }
    for (; j + 4 <= ct4; j += 4) {
        float4 v = *reinterpret_cast<const float4*>(s + j);
        acc = __fadd_rn(acc, v.x); acc = __fadd_rn(acc, v.y);
        acc = __fadd_rn(acc, v.z); acc = __fadd_rn(acc, v.w);
    }
    for (; j < ct; ++j) acc = __fadd_rn(acc, s[j]);

    c[k * DIM + lane] = __fdiv_rn(acc, (float)ct);   // 0/0 -> NaN matches ref
}

// ---------------- fallback gather (round-5 proven) ----------------
__global__ __launch_bounds__(64) void gather_k(
    const float* __restrict__ x, const int* __restrict__ order,
    const int* __restrict__ base, const int* __restrict__ cnt,
    float* __restrict__ c)
{
    const int k = blockIdx.x;
    const int lane = threadIdx.x;
    const int b0 = base[k];
    const int ct = cnt[k];
    float acc = 0.0f;
    int j = 0;
    for (; j + 32 <= ct; j += 32) {
        float v[32];
#pragma unroll
        for (int u = 0; u < 32; ++u)
            v[u] = x[(size_t)order[b0 + j + u] * DIM + lane];
#pragma unroll
        for (int u = 0; u < 32; ++u) acc = __fadd_rn(acc, v[u]);
    }
    for (; j < ct; ++j)
        acc = __fadd_rn(acc, x[(size_t)order[b0 + j] * DIM + lane]);
    c[k * DIM + lane] = __fdiv_rn(acc, (float)ct);
}

extern "C" void kernel_launch(void* const* d_in, const int* in_sizes, int n_in,
                              void* d_out, int out_size, void* d_ws, size_t ws_size,
                              hipStream_t stream)
{
    const float* x = (const float*)d_in[0];
    const int n = in_sizes[0] / DIM;          // 262144

    float* out_c = (float*)d_out;             // [256*64] centroids (working buffer too)
    float* out_labels = out_c + KC * DIM;     // [n] labels as floats

    const int nb = (n + 255) / 256;           // 1024
    const int nstride = n + 1024;             // padded sorted-position stride

    // workspace layout (256B-aligned blocks)
    size_t off = 0;
    auto alloc = [&](size_t bytes) -> size_t {
        size_t o = off; off = (off + bytes + 255) & ~(size_t)255; return o;
    };
    char* w = (char*)d_ws;
    int*   hist  = (int*)(w + alloc((size_t)nb * KC * sizeof(int)));
    int*   base  = (int*)(w + alloc(KC * sizeof(int)));
    int*   cnt   = (int*)(w + alloc(KC * sizeof(int)));
    int*   order = (int*)(w + alloc((size_t)nstride * sizeof(int)));
    const size_t med_need = off;
    float* buf   = (float*)(w + alloc((size_t)DIM * nstride * sizeof(float)));
    const size_t big_need = off;

    const bool big = (ws_size >= big_need);
    const bool med = (ws_size >= med_need);

    init_k<<<(KC * DIM + 255) / 256, 256, 0, stream>>>(x, out_c);
    if (big)  // pad slots of order must hold valid indices before first transpose
        hipMemsetAsync(order, 0, (size_t)nstride * sizeof(int), stream);

    for (int it = 0; it < NITER; ++it) {
        assign_hist_k<<<nb, 256, 0, stream>>>(x, out_c, out_labels, hist, n);
        if (med) {
            scan1_k<<<KC, 256, 0, stream>>>(hist, nb, cnt);
            scan2_k<<<1, 256, 0, stream>>>(cnt, base);
            scatter_k<<<nb, 256, 0, stream>>>(out_labels, hist, base, order, n);
            if (big) {
                transpose_k<<<nstride / 64, 256, 0, stream>>>(x, order, buf, nstride);
                sum_k<<<KC, 64, 0, stream>>>(buf, base, cnt, out_c, nstride);
            } else {
                gather_k<<<KC, 64, 0, stream>>>(x, order, base, cnt, out_c);
            }
        }
    }
}

// Round 9
// 2201.596 us; speedup vs baseline: 4.9747x; 1.5861x over previous
//
#include <hip/hip_runtime.h>

#define KC 256
#define DIM 64
#define NITER 10
#define KTILE 64   // clusters staged in LDS at a time (16 KiB)

// numpy pairwise sum for 64 elements, inputs already rounded f32:
// r[j] = a[j]+a[j+8]+...+a[j+56] (sequential), then ((r0+r1)+(r2+r3))+((r4+r5)+(r6+r7))
__device__ __forceinline__ float np_pairwise_sq64(const float* a) {
    float r[8];
#pragma unroll
    for (int j = 0; j < 8; ++j) r[j] = __fmul_rn(a[j], a[j]);
#pragma unroll
    for (int i = 8; i < 64; i += 8)
#pragma unroll
        for (int j = 0; j < 8; ++j)
            r[j] = __fadd_rn(r[j], __fmul_rn(a[i + j], a[i + j]));
    float t01 = __fadd_rn(r[0], r[1]), t23 = __fadd_rn(r[2], r[3]);
    float t45 = __fadd_rn(r[4], r[5]), t67 = __fadd_rn(r[6], r[7]);
    return __fadd_rn(__fadd_rn(t01, t23), __fadd_rn(t45, t67));
}

// ---------------- init: c = x[:K] ----------------
__global__ void init_k(const float* __restrict__ x, float* __restrict__ c) {
    const int idx = blockIdx.x * 256 + threadIdx.x;
    if (idx < KC * DIM) c[idx] = x[idx];
}

// ---------------- assign: 2 points/thread, LDS-tiled c (halves LDS-port bytes/FMA) ----------------
// Block = 128 threads covering 256 points [blockIdx*256, +256): thread t owns points
// (t) and (t+128). Same 256-point block ranges as scatter_k -> hist semantics unchanged.
__global__ __launch_bounds__(128) void assign_hist_k(
    const float* __restrict__ x, const float* __restrict__ c,
    float* __restrict__ labels, int* __restrict__ hist, int n)
{
    __shared__ float c_lds[KTILE * DIM];   // 16 KiB tile of centroids
    __shared__ float csq[KC];
    __shared__ int whist[4 * KC];          // rows: wave(2) x point-slot(2)
    const int t = threadIdx.x;

    for (int j = t; j < 4 * KC; j += 128) whist[j] = 0;
    for (int kk = t; kk < KC; kk += 128) {
        float cr[DIM];
        const float4* cp = reinterpret_cast<const float4*>(c + kk * DIM);
#pragma unroll
        for (int j = 0; j < DIM / 4; ++j) {
            float4 v = cp[j];
            cr[4 * j + 0] = v.x; cr[4 * j + 1] = v.y;
            cr[4 * j + 2] = v.z; cr[4 * j + 3] = v.w;
        }
        csq[kk] = np_pairwise_sq64(cr);
    }

    const int iA = blockIdx.x * 256 + t;
    const int iB = iA + 128;
    const bool vA = (iA < n), vB = (iB < n);

    float xra[DIM], xrb[DIM];
    {
        const float4* xv = reinterpret_cast<const float4*>(x + (size_t)(vA ? iA : 0) * DIM);
#pragma unroll
        for (int j = 0; j < DIM / 4; ++j) {
            float4 v = xv[j];
            xra[4 * j + 0] = v.x; xra[4 * j + 1] = v.y;
            xra[4 * j + 2] = v.z; xra[4 * j + 3] = v.w;
        }
        const float4* xw = reinterpret_cast<const float4*>(x + (size_t)(vB ? iB : 0) * DIM);
#pragma unroll
        for (int j = 0; j < DIM / 4; ++j) {
            float4 v = xw[j];
            xrb[4 * j + 0] = v.x; xrb[4 * j + 1] = v.y;
            xrb[4 * j + 2] = v.z; xrb[4 * j + 3] = v.w;
        }
    }
    const float xsqA = np_pairwise_sq64(xra);
    const float xsqB = np_pairwise_sq64(xrb);

    float bestA = __int_as_float(0x7f800000), bestB = bestA;
    int bkA = 0, bkB = 0, nanA = -1, nanB = -1;

    for (int tile = 0; tile < KC; tile += KTILE) {
        __syncthreads();   // also covers csq/whist init on first pass
        {
            const float4* src = reinterpret_cast<const float4*>(c + (size_t)tile * DIM);
            float4* dst = reinterpret_cast<float4*>(c_lds);
            for (int j = t; j < KTILE * DIM / 4; j += 128) dst[j] = src[j];
        }
        __syncthreads();

        for (int k0 = 0; k0 < KTILE; k0 += 8) {
            float accA[8], accB[8];
#pragma unroll
            for (int u = 0; u < 8; ++u) { accA[u] = 0.0f; accB[u] = 0.0f; }
            // cluster pairs x db: 2 cv reads feed 16 FMAs (4 chains of ILP)
#pragma unroll
            for (int up = 0; up < 8; up += 2) {
#pragma unroll
                for (int db = 0; db < DIM / 4; ++db) {
                    const float4 cv0 = *reinterpret_cast<const float4*>(c_lds + (k0 + up) * DIM + db * 4);
                    const float4 cv1 = *reinterpret_cast<const float4*>(c_lds + (k0 + up + 1) * DIM + db * 4);
                    const float a0 = xra[4 * db + 0], a1 = xra[4 * db + 1];
                    const float a2 = xra[4 * db + 2], a3 = xra[4 * db + 3];
                    const float b0 = xrb[4 * db + 0], b1 = xrb[4 * db + 1];
                    const float b2 = xrb[4 * db + 2], b3 = xrb[4 * db + 3];
                    accA[up]     = fmaf(a0, cv0.x, accA[up]);
                    accA[up]     = fmaf(a1, cv0.y, accA[up]);
                    accA[up]     = fmaf(a2, cv0.z, accA[up]);
                    accA[up]     = fmaf(a3, cv0.w, accA[up]);
                    accA[up + 1] = fmaf(a0, cv1.x, accA[up + 1]);
                    accA[up + 1] = fmaf(a1, cv1.y, accA[up + 1]);
                    accA[up + 1] = fmaf(a2, cv1.z, accA[up + 1]);
                    accA[up + 1] = fmaf(a3, cv1.w, accA[up + 1]);
                    accB[up]     = fmaf(b0, cv0.x, accB[up]);
                    accB[up]     = fmaf(b1, cv0.y, accB[up]);
                    accB[up]     = fmaf(b2, cv0.z, accB[up]);
                    accB[up]     = fmaf(b3, cv0.w, accB[up]);
                    accB[up + 1] = fmaf(b0, cv1.x, accB[up + 1]);
                    accB[up + 1] = fmaf(b1, cv1.y, accB[up + 1]);
                    accB[up + 1] = fmaf(b2, cv1.z, accB[up + 1]);
                    accB[up + 1] = fmaf(b3, cv1.w, accB[up + 1]);
                }
            }
#pragma unroll
            for (int u = 0; u < 8; ++u) {
                const int kk = tile + k0 + u;
                const float cs = csq[kk];
                const float dA = __fadd_rn(__fsub_rn(xsqA, 2.0f * accA[u]), cs);
                const float dB = __fadd_rn(__fsub_rn(xsqB, 2.0f * accB[u]), cs);
                if (dA < bestA) { bestA = dA; bkA = kk; }
                if (nanA < 0 && dA != dA) nanA = kk;   // numpy: first NaN wins
                if (dB < bestB) { bestB = dB; bkB = kk; }
                if (nanB < 0 && dB != dB) nanB = kk;
            }
        }
    }

    int lblA = 0, lblB = 0;
    if (vA) { lblA = (nanA >= 0 ? nanA : bkA); labels[iA] = (float)lblA; }
    if (vB) { lblB = (nanB >= 0 ? nanB : bkB); labels[iB] = (float)lblB; }

    // ballot-based per-wave group counts, one pass per point-slot (deterministic)
    const int lane = t & 63, w = t >> 6;   // w in {0,1}
    {
        unsigned long long same = __ballot(vA);
#pragma unroll
        for (int bit = 0; bit < 8; ++bit) {
            unsigned long long bb = __ballot((lblA >> bit) & 1);
            same &= ((lblA >> bit) & 1) ? bb : ~bb;
        }
        if (vA && lane == __builtin_ctzll(same))
            whist[(w * 2 + 0) * KC + lblA] = (int)__popcll(same);
    }
    {
        unsigned long long same = __ballot(vB);
#pragma unroll
        for (int bit = 0; bit < 8; ++bit) {
            unsigned long long bb = __ballot((lblB >> bit) & 1);
            same &= ((lblB >> bit) & 1) ? bb : ~bb;
        }
        if (vB && lane == __builtin_ctzll(same))
            whist[(w * 2 + 1) * KC + lblB] = (int)__popcll(same);
    }
    __syncthreads();
    for (int kk = t; kk < KC; kk += 128)
        hist[(size_t)blockIdx.x * KC + kk] =
            whist[kk] + whist[KC + kk] + whist[2 * KC + kk] + whist[3 * KC + kk];
}

// ---------------- scan1: per-cluster exclusive prefix over blocks ----------------
__global__ __launch_bounds__(256) void scan1_k(
    int* __restrict__ hist, int nb, int* __restrict__ cnt)
{
    __shared__ int sbuf[256];
    const int k = blockIdx.x;          // cluster
    const int t = threadIdx.x;
    const int epb = (nb + 255) / 256;  // entries per thread
    const int b0 = t * epb;

    int s = 0;
    for (int u = 0; u < epb; ++u) {
        const int b = b0 + u;
        if (b < nb) s += hist[(size_t)b * KC + k];
    }
    sbuf[t] = s;
    __syncthreads();
    int incl = s;
#pragma unroll
    for (int d = 1; d < 256; d <<= 1) {
        const int v = (t >= d) ? sbuf[t - d] : 0;
        __syncthreads();
        incl += v;
        sbuf[t] = incl;
        __syncthreads();
    }
    int run = incl - s;                // exclusive base for this chunk
    for (int u = 0; u < epb; ++u) {
        const int b = b0 + u;
        if (b < nb) {
            const int v = hist[(size_t)b * KC + k];
            hist[(size_t)b * KC + k] = run;
            run += v;
        }
    }
    if (t == 255) cnt[k] = incl;       // total count for cluster k
}

// ---------------- scan2: cluster bases (padded to 4) ----------------
__global__ __launch_bounds__(256) void scan2_k(
    const int* __restrict__ cnt, int* __restrict__ base)
{
    __shared__ int sbuf[256];
    const int t = threadIdx.x;
    const int padded = (cnt[t] + 3) & ~3;
    sbuf[t] = padded;
    __syncthreads();
    int incl = padded;
#pragma unroll
    for (int d = 1; d < 256; d <<= 1) {
        const int v = (t >= d) ? sbuf[t - d] : 0;
        __syncthreads();
        incl += v;
        sbuf[t] = incl;
        __syncthreads();
    }
    base[t] = incl - padded;
}

// ---------------- scatter: stable counting-sort placement (into padded segments) ----------------
__global__ __launch_bounds__(256) void scatter_k(
    const float* __restrict__ labels, const int* __restrict__ hist,
    const int* __restrict__ base, int* __restrict__ order, int n)
{
    __shared__ int whist[4 * KC];
    const int t = threadIdx.x;
    for (int j = t; j < 4 * KC; j += 256) whist[j] = 0;
    __syncthreads();

    const int i = blockIdx.x * 256 + t;
    const bool valid = (i < n);
    const int lbl = valid ? (int)labels[i] : 0;
    const int lane = t & 63, w = t >> 6;

    unsigned long long same = __ballot(valid);
#pragma unroll
    for (int bit = 0; bit < 8; ++bit) {
        unsigned long long bb = __ballot((lbl >> bit) & 1);
        same &= ((lbl >> bit) & 1) ? bb : ~bb;
    }
    const unsigned long long below = (1ull << lane) - 1ull;
    const int rank_wave = (int)__popcll(same & below);
    if (valid && lane == __builtin_ctzll(same))
        whist[w * KC + lbl] = (int)__popcll(same);
    __syncthreads();

    if (valid) {
        int off = rank_wave;
        for (int ww = 0; ww < w; ++ww) off += whist[ww * KC + lbl];
        const int pos = base[lbl] + hist[(size_t)blockIdx.x * KC + lbl] + off;
        order[pos] = i;
    }
}

// ---------------- permute + transpose: buf[d][pos] = x[order[pos]][d] ----------------
__global__ __launch_bounds__(256) void transpose_k(
    const float* __restrict__ x, const int* __restrict__ order,
    float* __restrict__ buf, int nstride)
{
    __shared__ float tile[64][65];
    __shared__ int idxs[64];
    const int t = threadIdx.x;
    const int p0 = blockIdx.x * 64;
    if (t < 64) idxs[t] = order[p0 + t];
    __syncthreads();
    const int w = t >> 6, lane = t & 63;
#pragma unroll
    for (int r = 0; r < 16; ++r) {
        const int row = w * 16 + r;
        tile[row][lane] = x[(size_t)idxs[row] * DIM + lane];   // coalesced 256B row read
    }
    __syncthreads();
#pragma unroll
    for (int r = 0; r < 16; ++r) {
        const int d = w * 16 + r;
        buf[(size_t)d * nstride + p0 + lane] = tile[lane][d];  // coalesced 256B write
    }
}

// ---------------- sum: contiguous float4 streams, exact ascending-order f32 chain ----------------
__global__ __launch_bounds__(64) void sum_k(
    const float* __restrict__ buf, const int* __restrict__ base,
    const int* __restrict__ cnt, float* __restrict__ c, int nstride)
{
    const int k = blockIdx.x;
    const int lane = threadIdx.x;          // = dim
    const int b0 = base[k];                // multiple of 4 -> 16B aligned
    const int ct = cnt[k];
    const float* s = buf + (size_t)lane * nstride + b0;

    float acc = 0.0f;
    int j = 0;
    const int ct4 = ct & ~3;
    for (; j + 32 <= ct4; j += 32) {
        float4 v[8];
#pragma unroll
        for (int u = 0; u < 8; ++u)
            v[u] = *reinterpret_cast<const float4*>(s + j + 4 * u);  // 8 loads in flight
#pragma unroll
        for (int u = 0; u < 8; ++u) {
            acc = __fadd_rn(acc, v[u].x); acc = __fadd_rn(acc, v[u].y);
            acc = __fadd_rn(acc, v[u].z); acc = __fadd_rn(acc, v[u].w);
        }
    }
    for (; j + 4 <= ct4; j += 4) {
        float4 v = *reinterpret_cast<const float4*>(s + j);
        acc = __fadd_rn(acc, v.x); acc = __fadd_rn(acc, v.y);
        acc = __fadd_rn(acc, v.z); acc = __fadd_rn(acc, v.w);
    }
    for (; j < ct; ++j) acc = __fadd_rn(acc, s[j]);

    c[k * DIM + lane] = __fdiv_rn(acc, (float)ct);   // 0/0 -> NaN matches ref
}

// ---------------- fallback gather (round-5 proven) ----------------
__global__ __launch_bounds__(64) void gather_k(
    const float* __restrict__ x, const int* __restrict__ order,
    const int* __restrict__ base, const int* __restrict__ cnt,
    float* __restrict__ c)
{
    const int k = blockIdx.x;
    const int lane = threadIdx.x;
    const int b0 = base[k];
    const int ct = cnt[k];
    float acc = 0.0f;
    int j = 0;
    for (; j + 32 <= ct; j += 32) {
        float v[32];
#pragma unroll
        for (int u = 0; u < 32; ++u)
            v[u] = x[(size_t)order[b0 + j + u] * DIM + lane];
#pragma unroll
        for (int u = 0; u < 32; ++u) acc = __fadd_rn(acc, v[u]);
    }
    for (; j < ct; ++j)
        acc = __fadd_rn(acc, x[(size_t)order[b0 + j] * DIM + lane]);
    c[k * DIM + lane] = __fdiv_rn(acc, (float)ct);
}

extern "C" void kernel_launch(void* const* d_in, const int* in_sizes, int n_in,
                              void* d_out, int out_size, void* d_ws, size_t ws_size,
                              hipStream_t stream)
{
    const float* x = (const float*)d_in[0];
    const int n = in_sizes[0] / DIM;          // 262144

    float* out_c = (float*)d_out;             // [256*64] centroids (working buffer too)
    float* out_labels = out_c + KC * DIM;     // [n] labels as floats

    const int nb = (n + 255) / 256;           // 1024 blocks of 256 points
    const int nstride = n + 1024;             // padded sorted-position stride

    // workspace layout (256B-aligned blocks)
    size_t off = 0;
    auto alloc = [&](size_t bytes) -> size_t {
        size_t o = off; off = (off + bytes + 255) & ~(size_t)255; return o;
    };
    char* w = (char*)d_ws;
    int*   hist  = (int*)(w + alloc((size_t)nb * KC * sizeof(int)));
    int*   base  = (int*)(w + alloc(KC * sizeof(int)));
    int*   cnt   = (int*)(w + alloc(KC * sizeof(int)));
    int*   order = (int*)(w + alloc((size_t)nstride * sizeof(int)));
    const size_t med_need = off;
    float* buf   = (float*)(w + alloc((size_t)DIM * nstride * sizeof(float)));
    const size_t big_need = off;

    const bool big = (ws_size >= big_need);
    const bool med = (ws_size >= med_need);

    init_k<<<(KC * DIM + 255) / 256, 256, 0, stream>>>(x, out_c);
    if (big)  // pad slots of order must hold valid indices before first transpose
        hipMemsetAsync(order, 0, (size_t)nstride * sizeof(int), stream);

    for (int it = 0; it < NITER; ++it) {
        assign_hist_k<<<nb, 128, 0, stream>>>(x, out_c, out_labels, hist, n);
        if (med) {
            scan1_k<<<KC, 256, 0, stream>>>(hist, nb, cnt);
            scan2_k<<<1, 256, 0, stream>>>(cnt, base);
            scatter_k<<<nb, 256, 0, stream>>>(out_labels, hist, base, order, n);
            if (big) {
                transpose_k<<<nstride / 64, 256, 0, stream>>>(x, order, buf, nstride);
                sum_k<<<KC, 64, 0, stream>>>(buf, base, cnt, out_c, nstride);
            } else {
                gather_k<<<KC, 64, 0, stream>>>(x, order, base, cnt, out_c);
            }
        }
    }
}

// Round 10
// 2167.045 us; speedup vs baseline: 5.0540x; 1.0159x over previous
//
#include <hip/hip_runtime.h>

#define KC 256
#define DIM 64
#define NITER 10
#define KTILE 64   // clusters staged in LDS at a time (16 KiB)
#define SB 64      // sum2 batch rows (64 floats/lane per buffer)

// numpy pairwise sum for 64 elements, inputs already rounded f32:
// r[j] = a[j]+a[j+8]+...+a[j+56] (sequential), then ((r0+r1)+(r2+r3))+((r4+r5)+(r6+r7))
__device__ __forceinline__ float np_pairwise_sq64(const float* a) {
    float r[8];
#pragma unroll
    for (int j = 0; j < 8; ++j) r[j] = __fmul_rn(a[j], a[j]);
#pragma unroll
    for (int i = 8; i < 64; i += 8)
#pragma unroll
        for (int j = 0; j < 8; ++j)
            r[j] = __fadd_rn(r[j], __fmul_rn(a[i + j], a[i + j]));
    float t01 = __fadd_rn(r[0], r[1]), t23 = __fadd_rn(r[2], r[3]);
    float t45 = __fadd_rn(r[4], r[5]), t67 = __fadd_rn(r[6], r[7]);
    return __fadd_rn(__fadd_rn(t01, t23), __fadd_rn(t45, t67));
}

// ---------------- init: c = x[:K] ----------------
__global__ void init_k(const float* __restrict__ x, float* __restrict__ c) {
    const int idx = blockIdx.x * 256 + threadIdx.x;
    if (idx < KC * DIM) c[idx] = x[idx];
}

// ---------------- assign: 2 points/thread, LDS-tiled c (round-9 proven) ----------------
__global__ __launch_bounds__(128) void assign_hist_k(
    const float* __restrict__ x, const float* __restrict__ c,
    float* __restrict__ labels, int* __restrict__ hist, int n)
{
    __shared__ float c_lds[KTILE * DIM];   // 16 KiB tile of centroids
    __shared__ float csq[KC];
    __shared__ int whist[4 * KC];          // rows: wave(2) x point-slot(2)
    const int t = threadIdx.x;

    for (int j = t; j < 4 * KC; j += 128) whist[j] = 0;
    for (int kk = t; kk < KC; kk += 128) {
        float cr[DIM];
        const float4* cp = reinterpret_cast<const float4*>(c + kk * DIM);
#pragma unroll
        for (int j = 0; j < DIM / 4; ++j) {
            float4 v = cp[j];
            cr[4 * j + 0] = v.x; cr[4 * j + 1] = v.y;
            cr[4 * j + 2] = v.z; cr[4 * j + 3] = v.w;
        }
        csq[kk] = np_pairwise_sq64(cr);
    }

    const int iA = blockIdx.x * 256 + t;
    const int iB = iA + 128;
    const bool vA = (iA < n), vB = (iB < n);

    float xra[DIM], xrb[DIM];
    {
        const float4* xv = reinterpret_cast<const float4*>(x + (size_t)(vA ? iA : 0) * DIM);
#pragma unroll
        for (int j = 0; j < DIM / 4; ++j) {
            float4 v = xv[j];
            xra[4 * j + 0] = v.x; xra[4 * j + 1] = v.y;
            xra[4 * j + 2] = v.z; xra[4 * j + 3] = v.w;
        }
        const float4* xw = reinterpret_cast<const float4*>(x + (size_t)(vB ? iB : 0) * DIM);
#pragma unroll
        for (int j = 0; j < DIM / 4; ++j) {
            float4 v = xw[j];
            xrb[4 * j + 0] = v.x; xrb[4 * j + 1] = v.y;
            xrb[4 * j + 2] = v.z; xrb[4 * j + 3] = v.w;
        }
    }
    const float xsqA = np_pairwise_sq64(xra);
    const float xsqB = np_pairwise_sq64(xrb);

    float bestA = __int_as_float(0x7f800000), bestB = bestA;
    int bkA = 0, bkB = 0, nanA = -1, nanB = -1;

    for (int tile = 0; tile < KC; tile += KTILE) {
        __syncthreads();   // also covers csq/whist init on first pass
        {
            const float4* src = reinterpret_cast<const float4*>(c + (size_t)tile * DIM);
            float4* dst = reinterpret_cast<float4*>(c_lds);
            for (int j = t; j < KTILE * DIM / 4; j += 128) dst[j] = src[j];
        }
        __syncthreads();

        for (int k0 = 0; k0 < KTILE; k0 += 8) {
            float accA[8], accB[8];
#pragma unroll
            for (int u = 0; u < 8; ++u) { accA[u] = 0.0f; accB[u] = 0.0f; }
#pragma unroll
            for (int up = 0; up < 8; up += 2) {
#pragma unroll
                for (int db = 0; db < DIM / 4; ++db) {
                    const float4 cv0 = *reinterpret_cast<const float4*>(c_lds + (k0 + up) * DIM + db * 4);
                    const float4 cv1 = *reinterpret_cast<const float4*>(c_lds + (k0 + up + 1) * DIM + db * 4);
                    const float a0 = xra[4 * db + 0], a1 = xra[4 * db + 1];
                    const float a2 = xra[4 * db + 2], a3 = xra[4 * db + 3];
                    const float b0 = xrb[4 * db + 0], b1 = xrb[4 * db + 1];
                    const float b2 = xrb[4 * db + 2], b3 = xrb[4 * db + 3];
                    accA[up]     = fmaf(a0, cv0.x, accA[up]);
                    accA[up]     = fmaf(a1, cv0.y, accA[up]);
                    accA[up]     = fmaf(a2, cv0.z, accA[up]);
                    accA[up]     = fmaf(a3, cv0.w, accA[up]);
                    accA[up + 1] = fmaf(a0, cv1.x, accA[up + 1]);
                    accA[up + 1] = fmaf(a1, cv1.y, accA[up + 1]);
                    accA[up + 1] = fmaf(a2, cv1.z, accA[up + 1]);
                    accA[up + 1] = fmaf(a3, cv1.w, accA[up + 1]);
                    accB[up]     = fmaf(b0, cv0.x, accB[up]);
                    accB[up]     = fmaf(b1, cv0.y, accB[up]);
                    accB[up]     = fmaf(b2, cv0.z, accB[up]);
                    accB[up]     = fmaf(b3, cv0.w, accB[up]);
                    accB[up + 1] = fmaf(b0, cv1.x, accB[up + 1]);
                    accB[up + 1] = fmaf(b1, cv1.y, accB[up + 1]);
                    accB[up + 1] = fmaf(b2, cv1.z, accB[up + 1]);
                    accB[up + 1] = fmaf(b3, cv1.w, accB[up + 1]);
                }
            }
#pragma unroll
            for (int u = 0; u < 8; ++u) {
                const int kk = tile + k0 + u;
                const float cs = csq[kk];
                const float dA = __fadd_rn(__fsub_rn(xsqA, 2.0f * accA[u]), cs);
                const float dB = __fadd_rn(__fsub_rn(xsqB, 2.0f * accB[u]), cs);
                if (dA < bestA) { bestA = dA; bkA = kk; }
                if (nanA < 0 && dA != dA) nanA = kk;   // numpy: first NaN wins
                if (dB < bestB) { bestB = dB; bkB = kk; }
                if (nanB < 0 && dB != dB) nanB = kk;
            }
        }
    }

    int lblA = 0, lblB = 0;
    if (vA) { lblA = (nanA >= 0 ? nanA : bkA); labels[iA] = (float)lblA; }
    if (vB) { lblB = (nanB >= 0 ? nanB : bkB); labels[iB] = (float)lblB; }

    const int lane = t & 63, w = t >> 6;   // w in {0,1}
    {
        unsigned long long same = __ballot(vA);
#pragma unroll
        for (int bit = 0; bit < 8; ++bit) {
            unsigned long long bb = __ballot((lblA >> bit) & 1);
            same &= ((lblA >> bit) & 1) ? bb : ~bb;
        }
        if (vA && lane == __builtin_ctzll(same))
            whist[(w * 2 + 0) * KC + lblA] = (int)__popcll(same);
    }
    {
        unsigned long long same = __ballot(vB);
#pragma unroll
        for (int bit = 0; bit < 8; ++bit) {
            unsigned long long bb = __ballot((lblB >> bit) & 1);
            same &= ((lblB >> bit) & 1) ? bb : ~bb;
        }
        if (vB && lane == __builtin_ctzll(same))
            whist[(w * 2 + 1) * KC + lblB] = (int)__popcll(same);
    }
    __syncthreads();
    for (int kk = t; kk < KC; kk += 128)
        hist[(size_t)blockIdx.x * KC + kk] =
            whist[kk] + whist[KC + kk] + whist[2 * KC + kk] + whist[3 * KC + kk];
}

// ---------------- scan1: per-cluster exclusive prefix over blocks ----------------
__global__ __launch_bounds__(256) void scan1_k(
    int* __restrict__ hist, int nb, int* __restrict__ cnt)
{
    __shared__ int sbuf[256];
    const int k = blockIdx.x;
    const int t = threadIdx.x;
    const int epb = (nb + 255) / 256;
    const int b0 = t * epb;

    int s = 0;
    for (int u = 0; u < epb; ++u) {
        const int b = b0 + u;
        if (b < nb) s += hist[(size_t)b * KC + k];
    }
    sbuf[t] = s;
    __syncthreads();
    int incl = s;
#pragma unroll
    for (int d = 1; d < 256; d <<= 1) {
        const int v = (t >= d) ? sbuf[t - d] : 0;
        __syncthreads();
        incl += v;
        sbuf[t] = incl;
        __syncthreads();
    }
    int run = incl - s;
    for (int u = 0; u < epb; ++u) {
        const int b = b0 + u;
        if (b < nb) {
            const int v = hist[(size_t)b * KC + k];
            hist[(size_t)b * KC + k] = run;
            run += v;
        }
    }
    if (t == 255) cnt[k] = incl;
}

// ---------------- scan2: cluster bases (padded to 64 rows for sum batching) ----------------
__global__ __launch_bounds__(256) void scan2_k(
    const int* __restrict__ cnt, int* __restrict__ base)
{
    __shared__ int sbuf[256];
    const int t = threadIdx.x;
    const int padded = (cnt[t] + 63) & ~63;
    sbuf[t] = padded;
    __syncthreads();
    int incl = padded;
#pragma unroll
    for (int d = 1; d < 256; d <<= 1) {
        const int v = (t >= d) ? sbuf[t - d] : 0;
        __syncthreads();
        incl += v;
        sbuf[t] = incl;
        __syncthreads();
    }
    base[t] = incl - padded;
}

// ---------------- scatter: stable counting-sort placement (into padded segments) ----------------
__global__ __launch_bounds__(256) void scatter_k(
    const float* __restrict__ labels, const int* __restrict__ hist,
    const int* __restrict__ base, int* __restrict__ order, int n)
{
    __shared__ int whist[4 * KC];
    const int t = threadIdx.x;
    for (int j = t; j < 4 * KC; j += 256) whist[j] = 0;
    __syncthreads();

    const int i = blockIdx.x * 256 + t;
    const bool valid = (i < n);
    const int lbl = valid ? (int)labels[i] : 0;
    const int lane = t & 63, w = t >> 6;

    unsigned long long same = __ballot(valid);
#pragma unroll
    for (int bit = 0; bit < 8; ++bit) {
        unsigned long long bb = __ballot((lbl >> bit) & 1);
        same &= ((lbl >> bit) & 1) ? bb : ~bb;
    }
    const unsigned long long below = (1ull << lane) - 1ull;
    const int rank_wave = (int)__popcll(same & below);
    if (valid && lane == __builtin_ctzll(same))
        whist[w * KC + lbl] = (int)__popcll(same);
    __syncthreads();

    if (valid) {
        int off = rank_wave;
        for (int ww = 0; ww < w; ++ww) off += whist[ww * KC + lbl];
        const int pos = base[lbl] + hist[(size_t)blockIdx.x * KC + lbl] + off;
        order[pos] = i;
    }
}

// ---------------- permute: xs[pos][d] = x[order[pos]][d]; pads (order<0) -> zero rows ----------------
__global__ __launch_bounds__(256) void permute_k(
    const float* __restrict__ x, const int* __restrict__ order,
    float* __restrict__ xs)
{
    const int r = blockIdx.x * 4 + (threadIdx.x >> 6);   // row (sorted position)
    const int d = threadIdx.x & 63;
    const int idx = order[r];                            // wave-uniform
    float v = 0.0f;
    if (idx >= 0) v = x[(size_t)idx * DIM + d];          // coalesced 256B row read
    xs[(size_t)r * DIM + d] = v;                         // coalesced 256B row write
}

// ---------------- sum2: sequential coalesced stream, 3-buffer pipelined exact f32 chain ----------------
#define LB(dst, off)                                                        \
    _Pragma("unroll")                                                       \
    for (int u = 0; u < SB; ++u) dst[u] = s[(size_t)((off) + u) * DIM];
#define AB(src)                                                             \
    _Pragma("unroll")                                                       \
    for (int u = 0; u < SB; ++u) acc = __fadd_rn(acc, src[u]);

__global__ __launch_bounds__(64) void sum2_k(
    const float* __restrict__ xs, const int* __restrict__ base,
    const int* __restrict__ cnt, float* __restrict__ c)
{
    const int k = blockIdx.x;
    const int lane = threadIdx.x;                 // = dim
    const int b0 = base[k];                       // multiple of 64
    const int ct = cnt[k];
    const int ctp = (ct + 63) & ~63;              // padded row count (zeros at tail)
    const float* s = xs + (size_t)b0 * DIM + lane;

    float va[SB], vb[SB], vc[SB];
    float acc = 0.0f;

    if (ctp >= 2 * SB) {
        LB(va, 0)
        LB(vb, SB)
        int j = 0;
        for (; j + 5 * SB <= ctp; j += 3 * SB) {
            LB(vc, j + 2 * SB)
            AB(va)
            LB(va, j + 3 * SB)
            AB(vb)
            LB(vb, j + 4 * SB)
            AB(vc)
        }
        const int rem = ctp - j;                  // 2*SB, 3*SB, or 4*SB
        AB(va)
        AB(vb)
        if (rem >= 3 * SB) {
            LB(vc, j + 2 * SB)
            AB(vc)
        }
        if (rem >= 4 * SB) {
            LB(va, j + 3 * SB)
            AB(va)
        }
    } else if (ctp == SB) {
        LB(va, 0)
        AB(va)
    }
    c[k * DIM + lane] = __fdiv_rn(acc, (float)ct);   // 0/0 -> NaN matches ref
}

// ---------------- fallback gather (round-5 proven, used only if d_ws too small) ----------------
__global__ __launch_bounds__(64) void gather_k(
    const float* __restrict__ x, const int* __restrict__ order,
    const int* __restrict__ base, const int* __restrict__ cnt,
    float* __restrict__ c)
{
    const int k = blockIdx.x;
    const int lane = threadIdx.x;
    const int b0 = base[k];
    const int ct = cnt[k];
    float acc = 0.0f;
    int j = 0;
    for (; j + 32 <= ct; j += 32) {
        float v[32];
#pragma unroll
        for (int u = 0; u < 32; ++u)
            v[u] = x[(size_t)order[b0 + j + u] * DIM + lane];
#pragma unroll
        for (int u = 0; u < 32; ++u) acc = __fadd_rn(acc, v[u]);
    }
    for (; j < ct; ++j)
        acc = __fadd_rn(acc, x[(size_t)order[b0 + j] * DIM + lane]);
    c[k * DIM + lane] = __fdiv_rn(acc, (float)ct);
}

extern "C" void kernel_launch(void* const* d_in, const int* in_sizes, int n_in,
                              void* d_out, int out_size, void* d_ws, size_t ws_size,
                              hipStream_t stream)
{
    const float* x = (const float*)d_in[0];
    const int n = in_sizes[0] / DIM;          // 262144

    float* out_c = (float*)d_out;             // [256*64] centroids (working buffer too)
    float* out_labels = out_c + KC * DIM;     // [n] labels as floats

    const int nb = (n + 255) / 256;           // 1024 blocks of 256 points
    const int nstride = n + KC * 64;          // padded sorted-position capacity (278528)

    // workspace layout (256B-aligned blocks)
    size_t off = 0;
    auto alloc = [&](size_t bytes) -> size_t {
        size_t o = off; off = (off + bytes + 255) & ~(size_t)255; return o;
    };
    char* w = (char*)d_ws;
    int*   hist  = (int*)(w + alloc((size_t)nb * KC * sizeof(int)));
    int*   base  = (int*)(w + alloc(KC * sizeof(int)));
    int*   cnt   = (int*)(w + alloc(KC * sizeof(int)));
    int*   order = (int*)(w + alloc((size_t)nstride * sizeof(int)));
    const size_t med_need = off;
    float* xs    = (float*)(w + alloc((size_t)nstride * DIM * sizeof(float)));
    const size_t big_need = off;

    const bool big = (ws_size >= big_need);
    const bool med = (ws_size >= med_need);

    init_k<<<(KC * DIM + 255) / 256, 256, 0, stream>>>(x, out_c);

    for (int it = 0; it < NITER; ++it) {
        assign_hist_k<<<nb, 128, 0, stream>>>(x, out_c, out_labels, hist, n);
        if (med) {
            scan1_k<<<KC, 256, 0, stream>>>(hist, nb, cnt);
            scan2_k<<<1, 256, 0, stream>>>(cnt, base);
            if (big)   // pads must be -1 for permute; real slots rewritten by scatter
                hipMemsetAsync(order, 0xFF, (size_t)nstride * sizeof(int), stream);
            scatter_k<<<nb, 256, 0, stream>>>(out_labels, hist, base, order, n);
            if (big) {
                permute_k<<<nstride / 4, 256, 0, stream>>>(x, order, xs);
                sum2_k<<<KC, 64, 0, stream>>>(xs, base, cnt, out_c);
            } else {
                gather_k<<<KC, 64, 0, stream>>>(x, order, base, cnt, out_c);
            }
        }
    }
}

// Round 11
// 2135.911 us; speedup vs baseline: 5.1276x; 1.0146x over previous
//
#include <hip/hip_runtime.h>

#define KC 256
#define DIM 64
#define NITER 10
#define KTILE 64   // clusters per half-tile staged in LDS (16 KiB each)
#define SB 64      // sum2 batch rows

// numpy pairwise sum for 64 elements, inputs already rounded f32:
// r[j] = a[j]+a[j+8]+...+a[j+56] (sequential), then ((r0+r1)+(r2+r3))+((r4+r5)+(r6+r7))
__device__ __forceinline__ float np_pairwise_sq64(const float* a) {
    float r[8];
#pragma unroll
    for (int j = 0; j < 8; ++j) r[j] = __fmul_rn(a[j], a[j]);
#pragma unroll
    for (int i = 8; i < 64; i += 8)
#pragma unroll
        for (int j = 0; j < 8; ++j)
            r[j] = __fadd_rn(r[j], __fmul_rn(a[i + j], a[i + j]));
    float t01 = __fadd_rn(r[0], r[1]), t23 = __fadd_rn(r[2], r[3]);
    float t45 = __fadd_rn(r[4], r[5]), t67 = __fadd_rn(r[6], r[7]);
    return __fadd_rn(__fadd_rn(t01, t23), __fadd_rn(t45, t67));
}

// ---------------- init: c = x[:K] ----------------
__global__ void init_k(const float* __restrict__ x, float* __restrict__ c) {
    const int idx = blockIdx.x * 256 + threadIdx.x;
    if (idx < KC * DIM) c[idx] = x[idx];
}

// ---------------- assign: K-split x2, 2 points/thread, LDS-tiled c ----------------
// Block = 256 threads over 256 points [blockIdx*256, +256).
// Thread t: points iA = b*256 + (t&127), iB = iA+128; clusters [khalf*128, +128), khalf = t>>7.
// Halves merged in LDS with exact numpy argmin semantics (first NaN wins; ties -> lower k).
__global__ __launch_bounds__(256) void assign_hist_k(
    const float* __restrict__ x, const float* __restrict__ c,
    float* __restrict__ labels, int* __restrict__ hist, int n)
{
    __shared__ float c_lds[2 * KTILE * DIM];   // 32 KiB: [low-half tile | high-half tile]
    __shared__ float csq[KC];                  // 1 KiB
    __shared__ int u_shm[4 * KC];              // 4 KiB: merge arrays, then reused as whist

    const int t = threadIdx.x;
    const int tl = t & 127;
    const int khalf = t >> 7;

    // csq for all clusters (numpy pairwise)
    for (int kk = t; kk < KC; kk += 256) {
        float cr[DIM];
        const float4* cp = reinterpret_cast<const float4*>(c + kk * DIM);
#pragma unroll
        for (int j = 0; j < DIM / 4; ++j) {
            float4 v = cp[j];
            cr[4 * j + 0] = v.x; cr[4 * j + 1] = v.y;
            cr[4 * j + 2] = v.z; cr[4 * j + 3] = v.w;
        }
        csq[kk] = np_pairwise_sq64(cr);
    }

    const int iA = blockIdx.x * 256 + tl;
    const int iB = iA + 128;
    const bool vA = (iA < n), vB = (iB < n);

    float xra[DIM], xrb[DIM];
    {
        const float4* xv = reinterpret_cast<const float4*>(x + (size_t)(vA ? iA : 0) * DIM);
#pragma unroll
        for (int j = 0; j < DIM / 4; ++j) {
            float4 v = xv[j];
            xra[4 * j + 0] = v.x; xra[4 * j + 1] = v.y;
            xra[4 * j + 2] = v.z; xra[4 * j + 3] = v.w;
        }
        const float4* xw = reinterpret_cast<const float4*>(x + (size_t)(vB ? iB : 0) * DIM);
#pragma unroll
        for (int j = 0; j < DIM / 4; ++j) {
            float4 v = xw[j];
            xrb[4 * j + 0] = v.x; xrb[4 * j + 1] = v.y;
            xrb[4 * j + 2] = v.z; xrb[4 * j + 3] = v.w;
        }
    }
    const float xsqA = np_pairwise_sq64(xra);
    const float xsqB = np_pairwise_sq64(xrb);

    float bestA = __int_as_float(0x7f800000), bestB = bestA;
    int bkA = khalf * 128, bkB = khalf * 128, nanA = -1, nanB = -1;

    for (int r = 0; r < 2; ++r) {
        __syncthreads();   // covers csq init (r=0) / prior-round compute (r=1)
        {
            const float4* srcL = reinterpret_cast<const float4*>(c + (size_t)(r * KTILE) * DIM);
            const float4* srcH = reinterpret_cast<const float4*>(c + (size_t)(128 + r * KTILE) * DIM);
            float4* dstL = reinterpret_cast<float4*>(c_lds);
            float4* dstH = reinterpret_cast<float4*>(c_lds + KTILE * DIM);
            for (int j = t; j < KTILE * DIM / 4; j += 256) { dstL[j] = srcL[j]; dstH[j] = srcH[j]; }
        }
        __syncthreads();

        const float* cbase = c_lds + khalf * KTILE * DIM;
        const int kgbase = khalf * 128 + r * KTILE;

        for (int k0 = 0; k0 < KTILE; k0 += 8) {
            float accA[8], accB[8];
#pragma unroll
            for (int u = 0; u < 8; ++u) { accA[u] = 0.0f; accB[u] = 0.0f; }
#pragma unroll
            for (int up = 0; up < 8; up += 2) {
#pragma unroll
                for (int db = 0; db < DIM / 4; ++db) {
                    const float4 cv0 = *reinterpret_cast<const float4*>(cbase + (k0 + up) * DIM + db * 4);
                    const float4 cv1 = *reinterpret_cast<const float4*>(cbase + (k0 + up + 1) * DIM + db * 4);
                    const float a0 = xra[4 * db + 0], a1 = xra[4 * db + 1];
                    const float a2 = xra[4 * db + 2], a3 = xra[4 * db + 3];
                    const float b0 = xrb[4 * db + 0], b1 = xrb[4 * db + 1];
                    const float b2 = xrb[4 * db + 2], b3 = xrb[4 * db + 3];
                    accA[up]     = fmaf(a0, cv0.x, accA[up]);
                    accA[up]     = fmaf(a1, cv0.y, accA[up]);
                    accA[up]     = fmaf(a2, cv0.z, accA[up]);
                    accA[up]     = fmaf(a3, cv0.w, accA[up]);
                    accA[up + 1] = fmaf(a0, cv1.x, accA[up + 1]);
                    accA[up + 1] = fmaf(a1, cv1.y, accA[up + 1]);
                    accA[up + 1] = fmaf(a2, cv1.z, accA[up + 1]);
                    accA[up + 1] = fmaf(a3, cv1.w, accA[up + 1]);
                    accB[up]     = fmaf(b0, cv0.x, accB[up]);
                    accB[up]     = fmaf(b1, cv0.y, accB[up]);
                    accB[up]     = fmaf(b2, cv0.z, accB[up]);
                    accB[up]     = fmaf(b3, cv0.w, accB[up]);
                    accB[up + 1] = fmaf(b0, cv1.x, accB[up + 1]);
                    accB[up + 1] = fmaf(b1, cv1.y, accB[up + 1]);
                    accB[up + 1] = fmaf(b2, cv1.z, accB[up + 1]);
                    accB[up + 1] = fmaf(b3, cv1.w, accB[up + 1]);
                }
            }
#pragma unroll
            for (int u = 0; u < 8; ++u) {
                const int kk = kgbase + k0 + u;
                const float cs = csq[kk];
                const float dA = __fadd_rn(__fsub_rn(xsqA, 2.0f * accA[u]), cs);
                const float dB = __fadd_rn(__fsub_rn(xsqB, 2.0f * accB[u]), cs);
                if (dA < bestA) { bestA = dA; bkA = kk; }
                if (nanA < 0 && dA != dA) nanA = kk;   // first NaN within half
                if (dB < bestB) { bestB = dB; bkB = kk; }
                if (nanB < 0 && dB != dB) nanB = kk;
            }
        }
    }

    // low half publishes its per-point results
    float* lowBest = reinterpret_cast<float*>(u_shm);
    int* lowBk = u_shm + 256;
    int* lowNan = u_shm + 512;
    if (khalf == 0) {
        lowBest[tl] = bestA; lowBk[tl] = bkA; lowNan[tl] = nanA;
        lowBest[tl + 128] = bestB; lowBk[tl + 128] = bkB; lowNan[tl + 128] = nanB;
    }
    __syncthreads();

    int lblA = 0, lblB = 0;
    if (khalf == 1) {
        const float loA = lowBest[tl]; const int loBkA = lowBk[tl]; const int loNanA = lowNan[tl];
        const float loB = lowBest[tl + 128]; const int loBkB = lowBk[tl + 128]; const int loNanB = lowNan[tl + 128];
        // numpy argmin over [0,256): first NaN wins (low half first); ties -> lower k
        if (loNanA >= 0) lblA = loNanA;
        else if (nanA >= 0) lblA = nanA;
        else lblA = (bestA < loA) ? bkA : loBkA;
        if (loNanB >= 0) lblB = loNanB;
        else if (nanB >= 0) lblB = nanB;
        else lblB = (bestB < loB) ? bkB : loBkB;
        if (vA) labels[iA] = (float)lblA;
        if (vB) labels[iB] = (float)lblB;
    }
    __syncthreads();            // merge reads complete; reuse u_shm as whist

    int* whist = u_shm;         // rows: wave-in-half(2) x point-slot(2)
    for (int j = t; j < 4 * KC; j += 256) whist[j] = 0;
    __syncthreads();

    if (khalf == 1) {           // waves 2-3 hold the merged labels
        const int lane = t & 63;
        const int w = (t >> 6) & 1;
        {
            unsigned long long same = __ballot(vA);
#pragma unroll
            for (int bit = 0; bit < 8; ++bit) {
                unsigned long long bb = __ballot((lblA >> bit) & 1);
                same &= ((lblA >> bit) & 1) ? bb : ~bb;
            }
            if (vA && lane == __builtin_ctzll(same))
                whist[(w * 2 + 0) * KC + lblA] = (int)__popcll(same);
        }
        {
            unsigned long long same = __ballot(vB);
#pragma unroll
            for (int bit = 0; bit < 8; ++bit) {
                unsigned long long bb = __ballot((lblB >> bit) & 1);
                same &= ((lblB >> bit) & 1) ? bb : ~bb;
            }
            if (vB && lane == __builtin_ctzll(same))
                whist[(w * 2 + 1) * KC + lblB] = (int)__popcll(same);
        }
    }
    __syncthreads();
    for (int kk = t; kk < KC; kk += 256)
        hist[(size_t)blockIdx.x * KC + kk] =
            whist[kk] + whist[KC + kk] + whist[2 * KC + kk] + whist[3 * KC + kk];
}

// ---------------- scan1: per-cluster exclusive prefix over blocks ----------------
__global__ __launch_bounds__(256) void scan1_k(
    int* __restrict__ hist, int nb, int* __restrict__ cnt)
{
    __shared__ int sbuf[256];
    const int k = blockIdx.x;
    const int t = threadIdx.x;
    const int epb = (nb + 255) / 256;
    const int b0 = t * epb;

    int s = 0;
    for (int u = 0; u < epb; ++u) {
        const int b = b0 + u;
        if (b < nb) s += hist[(size_t)b * KC + k];
    }
    sbuf[t] = s;
    __syncthreads();
    int incl = s;
#pragma unroll
    for (int d = 1; d < 256; d <<= 1) {
        const int v = (t >= d) ? sbuf[t - d] : 0;
        __syncthreads();
        incl += v;
        sbuf[t] = incl;
        __syncthreads();
    }
    int run = incl - s;
    for (int u = 0; u < epb; ++u) {
        const int b = b0 + u;
        if (b < nb) {
            const int v = hist[(size_t)b * KC + k];
            hist[(size_t)b * KC + k] = run;
            run += v;
        }
    }
    if (t == 255) cnt[k] = incl;
}

// ---------------- scan2: cluster bases (padded to 64 rows for sum batching) ----------------
__global__ __launch_bounds__(256) void scan2_k(
    const int* __restrict__ cnt, int* __restrict__ base)
{
    __shared__ int sbuf[256];
    const int t = threadIdx.x;
    const int padded = (cnt[t] + 63) & ~63;
    sbuf[t] = padded;
    __syncthreads();
    int incl = padded;
#pragma unroll
    for (int d = 1; d < 256; d <<= 1) {
        const int v = (t >= d) ? sbuf[t - d] : 0;
        __syncthreads();
        incl += v;
        sbuf[t] = incl;
        __syncthreads();
    }
    base[t] = incl - padded;
}

// ---------------- scatter: stable counting-sort placement (into padded segments) ----------------
__global__ __launch_bounds__(256) void scatter_k(
    const float* __restrict__ labels, const int* __restrict__ hist,
    const int* __restrict__ base, int* __restrict__ order, int n)
{
    __shared__ int whist[4 * KC];
    const int t = threadIdx.x;
    for (int j = t; j < 4 * KC; j += 256) whist[j] = 0;
    __syncthreads();

    const int i = blockIdx.x * 256 + t;
    const bool valid = (i < n);
    const int lbl = valid ? (int)labels[i] : 0;
    const int lane = t & 63, w = t >> 6;

    unsigned long long same = __ballot(valid);
#pragma unroll
    for (int bit = 0; bit < 8; ++bit) {
        unsigned long long bb = __ballot((lbl >> bit) & 1);
        same &= ((lbl >> bit) & 1) ? bb : ~bb;
    }
    const unsigned long long below = (1ull << lane) - 1ull;
    const int rank_wave = (int)__popcll(same & below);
    if (valid && lane == __builtin_ctzll(same))
        whist[w * KC + lbl] = (int)__popcll(same);
    __syncthreads();

    if (valid) {
        int off = rank_wave;
        for (int ww = 0; ww < w; ++ww) off += whist[ww * KC + lbl];
        const int pos = base[lbl] + hist[(size_t)blockIdx.x * KC + lbl] + off;
        order[pos] = i;
    }
}

// ---------------- permute: xs[pos][d] = x[order[pos]][d]; pads (order<0) -> zero rows ----------------
__global__ __launch_bounds__(256) void permute_k(
    const float* __restrict__ x, const int* __restrict__ order,
    float* __restrict__ xs)
{
    const int r = blockIdx.x * 4 + (threadIdx.x >> 6);   // row (sorted position)
    const int d = threadIdx.x & 63;
    const int idx = order[r];                            // wave-uniform
    float v = 0.0f;
    if (idx >= 0) v = x[(size_t)idx * DIM + d];          // coalesced 256B row read
    xs[(size_t)r * DIM + d] = v;                         // coalesced 256B row write
}

// ---------------- sum2: sequential coalesced stream, 3-buffer pipelined exact f32 chain ----------------
#define LB(dst, off)                                                        \
    _Pragma("unroll")                                                       \
    for (int u = 0; u < SB; ++u) dst[u] = s[(size_t)((off) + u) * DIM];
#define AB(src)                                                             \
    _Pragma("unroll")                                                       \
    for (int u = 0; u < SB; ++u) acc = __fadd_rn(acc, src[u]);

__global__ __launch_bounds__(64) void sum2_k(
    const float* __restrict__ xs, const int* __restrict__ base,
    const int* __restrict__ cnt, float* __restrict__ c)
{
    const int k = blockIdx.x;
    const int lane = threadIdx.x;                 // = dim
    const int b0 = base[k];                       // multiple of 64
    const int ct = cnt[k];
    const int ctp = (ct + 63) & ~63;              // padded row count (zeros at tail)
    const float* s = xs + (size_t)b0 * DIM + lane;

    float va[SB], vb[SB], vc[SB];
    float acc = 0.0f;

    if (ctp >= 2 * SB) {
        LB(va, 0)
        LB(vb, SB)
        int j = 0;
        for (; j + 5 * SB <= ctp; j += 3 * SB) {
            LB(vc, j + 2 * SB)
            AB(va)
            LB(va, j + 3 * SB)
            AB(vb)
            LB(vb, j + 4 * SB)
            AB(vc)
        }
        const int rem = ctp - j;                  // 2*SB, 3*SB, or 4*SB
        AB(va)
        AB(vb)
        if (rem >= 3 * SB) {
            LB(vc, j + 2 * SB)
            AB(vc)
        }
        if (rem >= 4 * SB) {
            LB(va, j + 3 * SB)
            AB(va)
        }
    } else if (ctp == SB) {
        LB(va, 0)
        AB(va)
    }
    c[k * DIM + lane] = __fdiv_rn(acc, (float)ct);   // 0/0 -> NaN matches ref
}

// ---------------- fallback gather (round-5 proven, used only if d_ws too small) ----------------
__global__ __launch_bounds__(64) void gather_k(
    const float* __restrict__ x, const int* __restrict__ order,
    const int* __restrict__ base, const int* __restrict__ cnt,
    float* __restrict__ c)
{
    const int k = blockIdx.x;
    const int lane = threadIdx.x;
    const int b0 = base[k];
    const int ct = cnt[k];
    float acc = 0.0f;
    int j = 0;
    for (; j + 32 <= ct; j += 32) {
        float v[32];
#pragma unroll
        for (int u = 0; u < 32; ++u)
            v[u] = x[(size_t)order[b0 + j + u] * DIM + lane];
#pragma unroll
        for (int u = 0; u < 32; ++u) acc = __fadd_rn(acc, v[u]);
    }
    for (; j < ct; ++j)
        acc = __fadd_rn(acc, x[(size_t)order[b0 + j] * DIM + lane]);
    c[k * DIM + lane] = __fdiv_rn(acc, (float)ct);
}

extern "C" void kernel_launch(void* const* d_in, const int* in_sizes, int n_in,
                              void* d_out, int out_size, void* d_ws, size_t ws_size,
                              hipStream_t stream)
{
    const float* x = (const float*)d_in[0];
    const int n = in_sizes[0] / DIM;          // 262144

    float* out_c = (float*)d_out;             // [256*64] centroids (working buffer too)
    float* out_labels = out_c + KC * DIM;     // [n] labels as floats

    const int nb = (n + 255) / 256;           // 1024 blocks of 256 points
    const int nstride = n + KC * 64;          // padded sorted-position capacity

    // workspace layout (256B-aligned blocks)
    size_t off = 0;
    auto alloc = [&](size_t bytes) -> size_t {
        size_t o = off; off = (off + bytes + 255) & ~(size_t)255; return o;
    };
    char* w = (char*)d_ws;
    int*   hist  = (int*)(w + alloc((size_t)nb * KC * sizeof(int)));
    int*   base  = (int*)(w + alloc(KC * sizeof(int)));
    int*   cnt   = (int*)(w + alloc(KC * sizeof(int)));
    int*   order = (int*)(w + alloc((size_t)nstride * sizeof(int)));
    const size_t med_need = off;
    float* xs    = (float*)(w + alloc((size_t)nstride * DIM * sizeof(float)));
    const size_t big_need = off;

    const bool big = (ws_size >= big_need);
    const bool med = (ws_size >= med_need);

    init_k<<<(KC * DIM + 255) / 256, 256, 0, stream>>>(x, out_c);

    for (int it = 0; it < NITER; ++it) {
        assign_hist_k<<<nb, 256, 0, stream>>>(x, out_c, out_labels, hist, n);
        if (med) {
            scan1_k<<<KC, 256, 0, stream>>>(hist, nb, cnt);
            scan2_k<<<1, 256, 0, stream>>>(cnt, base);
            if (big)   // pads must be -1 for permute; real slots rewritten by scatter
                hipMemsetAsync(order, 0xFF, (size_t)nstride * sizeof(int), stream);
            scatter_k<<<nb, 256, 0, stream>>>(out_labels, hist, base, order, n);
            if (big) {
                permute_k<<<nstride / 4, 256, 0, stream>>>(x, order, xs);
                sum2_k<<<KC, 64, 0, stream>>>(xs, base, cnt, out_c);
            } else {
                gather_k<<<KC, 64, 0, stream>>>(x, order, base, cnt, out_c);
            }
        }
    }
}